// Round 18
// baseline (233.284 us; speedup 1.0000x reference)
//
#include <hip/hip_runtime.h>
#include <stdint.h>
#include <math.h>

typedef __bf16 bf16_t;
typedef __bf16 bf16x8 __attribute__((ext_vector_type(8)));
typedef __bf16 bf16x4 __attribute__((ext_vector_type(4)));
typedef float f32x4 __attribute__((ext_vector_type(4)));

#define GLD_LDS16(g, l)                                             \
    __builtin_amdgcn_global_load_lds(                               \
        (const __attribute__((address_space(1))) void*)(g),         \
        (__attribute__((address_space(3))) void*)(l), 16, 0, 0)

#define WAITV(N) asm volatile("s_waitcnt vmcnt(" #N ")" ::: "memory")
#define BARRIER() do { __builtin_amdgcn_sched_barrier(0);           \
                       __builtin_amdgcn_s_barrier();                \
                       __builtin_amdgcn_sched_barrier(0); } while (0)

// ---------------------------------------------------------------------------
// prep: fused weight transposes (wq/wk/wv -> Bh panel) + RoPE tables +
// hs fp32->bf16 conv.
// ---------------------------------------------------------------------------
__global__ __launch_bounds__(256)
void prep(const float* __restrict__ hs, bf16_t* __restrict__ hsb,
          const float* __restrict__ wq, const float* __restrict__ wk,
          const float* __restrict__ wv, bf16_t* __restrict__ Bh,
          float* __restrict__ ct, float* __restrict__ st)
{
    const int b = blockIdx.x;
    if (b >= 4608) {                       // conv: 10240 blocks x 256 x 4
        int i = (b - 4608) * 256 + threadIdx.x;
        float4 v = ((const float4*)hs)[i];
        bf16x4 o = { (bf16_t)v.x, (bf16_t)v.y, (bf16_t)v.z, (bf16_t)v.w };
        ((bf16x4*)hsb)[i] = o;
        return;
    }
    if (b >= 2560) {                       // rope tables: 2048 blocks
        int t = (b - 2560) * 256 + threadIdx.x;   // 4096*128
        int s = t >> 7, j = t & 127;
        double inv = exp2((double)j * (-13.28771237954945 / 128.0));
        double ang = fmod((double)s * inv, 6.283185307179586476925286766559);
        ct[t] = (float)cos(ang);
        st[t] = (float)sin(ang);
        return;
    }
    const float* src; bf16_t* dst; int C, bx, by;
    if (b < 1280)      { src = wq; dst = Bh;                          C = 2048; bx = b % 32;          by = b / 32; }
    else if (b < 1920) { src = wk; dst = Bh + (size_t)2048 * 2560;    C = 1024; bx = (b - 1280) % 16; by = (b - 1280) / 16; }
    else               { src = wv; dst = Bh + (size_t)3072 * 2560;    C = 1024; bx = (b - 1920) % 16; by = (b - 1920) / 16; }
    const int R = 2560;
    __shared__ float t[64][65];
    const int r0 = by * 64, c0 = bx * 64;
#pragma unroll
    for (int i = 0; i < 16; ++i) {
        int f = threadIdx.x + i * 256;
        int r = f >> 6, c = f & 63;
        t[r][c] = src[(size_t)(r0 + r) * C + c0 + c];
    }
    __syncthreads();
#pragma unroll
    for (int i = 0; i < 16; ++i) {
        int f = threadIdx.x + i * 256;
        int r = f >> 6, c = f & 63;
        dst[(size_t)(c0 + r) * R + r0 + c] = (bf16_t)t[c][r];
    }
}

// ---------------------------------------------------------------------------
// GEMM1 (fused qkv), 8-phase 256x256 tile, BK=64, 8 waves (2Mx4N), 128 KiB
// LDS double-buffer, XOR-swizzled, counted vmcnt; XCD-chunked block swizzle.
// ---------------------------------------------------------------------------
__global__ __launch_bounds__(512, 2)
void gemm1(const bf16_t* __restrict__ A, const bf16_t* __restrict__ Bh,
           bf16_t* __restrict__ qb, bf16_t* __restrict__ kb,
           bf16_t* __restrict__ vt)
{
    __shared__ __attribute__((aligned(16))) char smem[131072];
    const int tid = threadIdx.x, lane = tid & 63, wid = tid >> 6;
    const int g = lane >> 4, c16 = lane & 15;
    const int wm = wid >> 2, wn = wid & 3;          // 2 x 4 wave grid
    const int bid = blockIdx.y * 16 + blockIdx.x;
    const int nb = (bid & 7) * 32 + (bid >> 3);
    const int m0 = (nb >> 4) * 256, n0 = (nb & 15) * 256;
    const int swz = c16 & 7;
    const int NT = 40;                               // 2560 / 64

    f32x4 acc[8][4];
#pragma unroll
    for (int m = 0; m < 8; ++m)
#pragma unroll
        for (int n = 0; n < 4; ++n) acc[m][n] = (f32x4)(0.f);

    auto STAGE_A = [&](int dbuf, int kt, int half) {
#pragma unroll
        for (int pl = 0; pl < 2; ++pl) {
            int c = pl * 512 + tid;
            int row = c >> 3, b = c & 7;
            GLD_LDS16(A + (size_t)(m0 + half * 128 + row) * 2560 + kt * 64
                        + ((b ^ (row & 7)) << 3),
                      smem + dbuf * 65536 + half * 16384
                        + (pl * 512 + wid * 64) * 16);
        }
    };
    auto STAGE_B = [&](int dbuf, int kt, int qp) {
#pragma unroll
        for (int pl = 0; pl < 2; ++pl) {
            int c = pl * 512 + tid;
            int u = c >> 3, b = c & 7;
            int row = ((u >> 5) << 6) + qp * 32 + (u & 31);
            int u0 = pl * 64 + wid * 8;
            int row0 = ((u0 >> 5) << 6) + qp * 32 + (u0 & 31);
            GLD_LDS16(Bh + (size_t)(n0 + row) * 2560 + kt * 64
                        + ((b ^ (row & 7)) << 3),
                      smem + dbuf * 65536 + 32768 + row0 * 128);
        }
    };

    STAGE_A(0, 0, 0); STAGE_A(0, 0, 1); STAGE_B(0, 0, 0); STAGE_B(0, 0, 1);
    WAITV(2);
    BARRIER();

    for (int t = 0; t < NT; ++t) {
        const int buf = t & 1, nbuf = buf ^ 1;
        const char* Ab = smem + buf * 65536;
        const char* Bb = smem + buf * 65536 + 32768;
        auto rdA = [&](int m, int kk) {
            return *(const bf16x8*)(Ab + (wm * 128 + m * 16 + c16) * 128
                                       + (((kk * 4 + g) ^ swz) << 4));
        };
        auto rdB = [&](int n, int kk) {
            return *(const bf16x8*)(Bb + (wn * 64 + n * 16 + c16) * 128
                                       + (((kk * 4 + g) ^ swz) << 4));
        };
        bf16x8 a[8], b0, b1, b2, b3;

        // ---- P0 ------------------------------------------------------
#pragma unroll
        for (int m = 0; m < 8; ++m) a[m] = rdA(m, 0);
        b0 = rdB(0, 0); b1 = rdB(1, 0);
        if (t + 1 < NT) STAGE_A(nbuf, t + 1, 0);
        BARRIER();
        __builtin_amdgcn_s_setprio(1);
#pragma unroll
        for (int m = 0; m < 8; ++m) {
            acc[m][0] = __builtin_amdgcn_mfma_f32_16x16x32_bf16(a[m], b0, acc[m][0], 0, 0, 0);
            acc[m][1] = __builtin_amdgcn_mfma_f32_16x16x32_bf16(a[m], b1, acc[m][1], 0, 0, 0);
        }
        __builtin_amdgcn_s_setprio(0);
        if (t + 1 < NT) { WAITV(2); } else { WAITV(0); }
        BARRIER();

        // ---- P1 ------------------------------------------------------
        b2 = rdB(2, 0); b3 = rdB(3, 0);
        if (t + 1 < NT) STAGE_A(nbuf, t + 1, 1);
        BARRIER();
        __builtin_amdgcn_s_setprio(1);
#pragma unroll
        for (int m = 0; m < 8; ++m) {
            acc[m][2] = __builtin_amdgcn_mfma_f32_16x16x32_bf16(a[m], b2, acc[m][2], 0, 0, 0);
            acc[m][3] = __builtin_amdgcn_mfma_f32_16x16x32_bf16(a[m], b3, acc[m][3], 0, 0, 0);
        }
        __builtin_amdgcn_s_setprio(0);
        BARRIER();

        // ---- P2 ------------------------------------------------------
#pragma unroll
        for (int m = 0; m < 8; ++m) a[m] = rdA(m, 1);
        b0 = rdB(0, 1); b1 = rdB(1, 1);
        if (t + 1 < NT) STAGE_B(nbuf, t + 1, 0);
        BARRIER();
        __builtin_amdgcn_s_setprio(1);
#pragma unroll
        for (int m = 0; m < 8; ++m) {
            acc[m][0] = __builtin_amdgcn_mfma_f32_16x16x32_bf16(a[m], b0, acc[m][0], 0, 0, 0);
            acc[m][1] = __builtin_amdgcn_mfma_f32_16x16x32_bf16(a[m], b1, acc[m][1], 0, 0, 0);
        }
        __builtin_amdgcn_s_setprio(0);
        BARRIER();

        // ---- P3 ------------------------------------------------------
        b2 = rdB(2, 1); b3 = rdB(3, 1);
        if (t + 1 < NT) STAGE_B(nbuf, t + 1, 1);
        BARRIER();
        __builtin_amdgcn_s_setprio(1);
#pragma unroll
        for (int m = 0; m < 8; ++m) {
            acc[m][2] = __builtin_amdgcn_mfma_f32_16x16x32_bf16(a[m], b2, acc[m][2], 0, 0, 0);
            acc[m][3] = __builtin_amdgcn_mfma_f32_16x16x32_bf16(a[m], b3, acc[m][3], 0, 0, 0);
        }
        __builtin_amdgcn_s_setprio(0);
        if (t + 1 < NT) WAITV(2);
        BARRIER();
    }

    if (n0 < 2048) {          // q region
#pragma unroll
        for (int m = 0; m < 8; ++m)
#pragma unroll
            for (int n = 0; n < 4; ++n) {
                int col = n0 + wn * 64 + n * 16 + c16;
                int rowb = m0 + wm * 128 + m * 16 + g * 4;
#pragma unroll
                for (int r = 0; r < 4; ++r)
                    qb[(size_t)(rowb + r) * 2048 + col] = (bf16_t)acc[m][n][r];
            }
    } else if (n0 < 3072) {   // k region (raw, re-tiled by norm_qk)
#pragma unroll
        for (int m = 0; m < 8; ++m)
#pragma unroll
            for (int n = 0; n < 4; ++n) {
                int col = n0 + wn * 64 + n * 16 + c16 - 2048;
                int rowb = m0 + wm * 128 + m * 16 + g * 4;
#pragma unroll
                for (int r = 0; r < 4; ++r)
                    kb[(size_t)(rowb + r) * 1024 + col] = (bf16_t)acc[m][n][r];
            }
    } else {                  // v region -> vt2 tiled + swizzled
#pragma unroll
        for (int m = 0; m < 8; ++m)
#pragma unroll
            for (int n = 0; n < 4; ++n) {
                int d = n0 + wn * 64 + n * 16 + c16 - 3072;
                int rowb = m0 + wm * 128 + m * 16 + g * 4;
                int kvh_ = d >> 8, dd = d & 255;
                int kt = rowb >> 5, key = rowb & 31;
                bf16x4 hv;
#pragma unroll
                for (int r = 0; r < 4; ++r) hv[r] = (bf16_t)acc[m][n][r];
                size_t off = (size_t)kvh_ * 1048576 + (size_t)kt * 8192
                           + dd * 32 + (((key >> 3) ^ (dd & 3)) << 3) + (key & 7);
                *(bf16x4*)(vt + off) = hv;
            }
    }
}

// ---------------------------------------------------------------------------
// GEMM2, same template/schedule, K = 2048 -> NT = 32, fp32 out; XCD swizzle.
// ---------------------------------------------------------------------------
__global__ __launch_bounds__(512, 2)
void gemm2p(const bf16_t* __restrict__ A, const bf16_t* __restrict__ Bh,
            float* __restrict__ C)
{
    __shared__ __attribute__((aligned(16))) char smem[131072];
    const int tid = threadIdx.x, lane = tid & 63, wid = tid >> 6;
    const int g = lane >> 4, c16 = lane & 15;
    const int wm = wid >> 2, wn = wid & 3;
    const int bid = blockIdx.y * 10 + blockIdx.x;
    const int nb = (bid & 7) * 20 + (bid >> 3);
    const int m0 = (nb / 10) * 256, n0 = (nb % 10) * 256;
    const int swz = c16 & 7;
    const int NT = 32;                               // 2048 / 64

    f32x4 acc[8][4];
#pragma unroll
    for (int m = 0; m < 8; ++m)
#pragma unroll
        for (int n = 0; n < 4; ++n) acc[m][n] = (f32x4)(0.f);

    auto STAGE_A = [&](int dbuf, int kt, int half) {
#pragma unroll
        for (int pl = 0; pl < 2; ++pl) {
            int c = pl * 512 + tid;
            int row = c >> 3, b = c & 7;
            GLD_LDS16(A + (size_t)(m0 + half * 128 + row) * 2048 + kt * 64
                        + ((b ^ (row & 7)) << 3),
                      smem + dbuf * 65536 + half * 16384
                        + (pl * 512 + wid * 64) * 16);
        }
    };
    auto STAGE_B = [&](int dbuf, int kt, int qp) {
#pragma unroll
        for (int pl = 0; pl < 2; ++pl) {
            int c = pl * 512 + tid;
            int u = c >> 3, b = c & 7;
            int row = ((u >> 5) << 6) + qp * 32 + (u & 31);
            int u0 = pl * 64 + wid * 8;
            int row0 = ((u0 >> 5) << 6) + qp * 32 + (u0 & 31);
            GLD_LDS16(Bh + (size_t)(n0 + row) * 2048 + kt * 64
                        + ((b ^ (row & 7)) << 3),
                      smem + dbuf * 65536 + 32768 + row0 * 128);
        }
    };

    STAGE_A(0, 0, 0); STAGE_A(0, 0, 1); STAGE_B(0, 0, 0); STAGE_B(0, 0, 1);
    WAITV(2);
    BARRIER();

    for (int t = 0; t < NT; ++t) {
        const int buf = t & 1, nbuf = buf ^ 1;
        const char* Ab = smem + buf * 65536;
        const char* Bb = smem + buf * 65536 + 32768;
        auto rdA = [&](int m, int kk) {
            return *(const bf16x8*)(Ab + (wm * 128 + m * 16 + c16) * 128
                                       + (((kk * 4 + g) ^ swz) << 4));
        };
        auto rdB = [&](int n, int kk) {
            return *(const bf16x8*)(Bb + (wn * 64 + n * 16 + c16) * 128
                                       + (((kk * 4 + g) ^ swz) << 4));
        };
        bf16x8 a[8], b0, b1, b2, b3;

#pragma unroll
        for (int m = 0; m < 8; ++m) a[m] = rdA(m, 0);
        b0 = rdB(0, 0); b1 = rdB(1, 0);
        if (t + 1 < NT) STAGE_A(nbuf, t + 1, 0);
        BARRIER();
        __builtin_amdgcn_s_setprio(1);
#pragma unroll
        for (int m = 0; m < 8; ++m) {
            acc[m][0] = __builtin_amdgcn_mfma_f32_16x16x32_bf16(a[m], b0, acc[m][0], 0, 0, 0);
            acc[m][1] = __builtin_amdgcn_mfma_f32_16x16x32_bf16(a[m], b1, acc[m][1], 0, 0, 0);
        }
        __builtin_amdgcn_s_setprio(0);
        if (t + 1 < NT) { WAITV(2); } else { WAITV(0); }
        BARRIER();

        b2 = rdB(2, 0); b3 = rdB(3, 0);
        if (t + 1 < NT) STAGE_A(nbuf, t + 1, 1);
        BARRIER();
        __builtin_amdgcn_s_setprio(1);
#pragma unroll
        for (int m = 0; m < 8; ++m) {
            acc[m][2] = __builtin_amdgcn_mfma_f32_16x16x32_bf16(a[m], b2, acc[m][2], 0, 0, 0);
            acc[m][3] = __builtin_amdgcn_mfma_f32_16x16x32_bf16(a[m], b3, acc[m][3], 0, 0, 0);
        }
        __builtin_amdgcn_s_setprio(0);
        BARRIER();

#pragma unroll
        for (int m = 0; m < 8; ++m) a[m] = rdA(m, 1);
        b0 = rdB(0, 1); b1 = rdB(1, 1);
        if (t + 1 < NT) STAGE_B(nbuf, t + 1, 0);
        BARRIER();
        __builtin_amdgcn_s_setprio(1);
#pragma unroll
        for (int m = 0; m < 8; ++m) {
            acc[m][0] = __builtin_amdgcn_mfma_f32_16x16x32_bf16(a[m], b0, acc[m][0], 0, 0, 0);
            acc[m][1] = __builtin_amdgcn_mfma_f32_16x16x32_bf16(a[m], b1, acc[m][1], 0, 0, 0);
        }
        __builtin_amdgcn_s_setprio(0);
        BARRIER();

        b2 = rdB(2, 1); b3 = rdB(3, 1);
        if (t + 1 < NT) STAGE_B(nbuf, t + 1, 1);
        BARRIER();
        __builtin_amdgcn_s_setprio(1);
#pragma unroll
        for (int m = 0; m < 8; ++m) {
            acc[m][2] = __builtin_amdgcn_mfma_f32_16x16x32_bf16(a[m], b2, acc[m][2], 0, 0, 0);
            acc[m][3] = __builtin_amdgcn_mfma_f32_16x16x32_bf16(a[m], b3, acc[m][3], 0, 0, 0);
        }
        __builtin_amdgcn_s_setprio(0);
        if (t + 1 < NT) WAITV(2);
        BARRIER();
    }

#pragma unroll
    for (int m = 0; m < 8; ++m)
#pragma unroll
        for (int n = 0; n < 4; ++n) {
            int col = n0 + wn * 64 + n * 16 + c16;
            int rowb = m0 + wm * 128 + m * 16 + g * 4;
#pragma unroll
            for (int r = 0; r < 4; ++r)
                C[(size_t)(rowb + r) * 2560 + col] = acc[m][n][r];
        }
}

// ---------------------------------------------------------------------------
// Fused RMSNorm + RoPE + wo-transpose.
// ---------------------------------------------------------------------------
__global__ __launch_bounds__(512)
void norm_qk(bf16_t* __restrict__ qb, const bf16_t* __restrict__ kraw,
             bf16_t* __restrict__ kb2, const float* __restrict__ qw,
             const float* __restrict__ kw, const float* __restrict__ ct,
             const float* __restrict__ st, const float* __restrict__ wo,
             bf16_t* __restrict__ woh)
{
    __shared__ float tt[2][64][65];
    const int s = blockIdx.x, t = threadIdx.x;
    if (s >= 4096) {          // wo transpose: 2 tiles per block
        const int half = t >> 8, tl = t & 255;
        const int tileIdx = (s - 4096) * 2 + half;   // 0..1279
        const int bx = tileIdx % 40, by = tileIdx / 40;
        const int r0 = by * 64, c0 = bx * 64;
#pragma unroll
        for (int i = 0; i < 16; ++i) {
            int f = tl + i * 256;
            int r = f >> 6, c = f & 63;
            tt[half][r][c] = wo[(size_t)(r0 + r) * 2560 + c0 + c];
        }
        __syncthreads();
#pragma unroll
        for (int i = 0; i < 16; ++i) {
            int f = tl + i * 256;
            int r = f >> 6, c = f & 63;
            woh[(size_t)(c0 + r) * 2048 + r0 + c] = (bf16_t)tt[half][c][r];
        }
        return;
    }
    if (t < 256) {
        const int h = t >> 5, l = t & 31;
        bf16_t* base = qb + (size_t)s * 2048 + h * 256 + l * 8;
        bf16x8 hv = *(const bf16x8*)base;
        float x[8], ss = 0.f;
#pragma unroll
        for (int j = 0; j < 8; ++j) { x[j] = (float)hv[j]; ss += x[j] * x[j]; }
#pragma unroll
        for (int mk = 1; mk < 32; mk <<= 1) ss += __shfl_xor(ss, mk);
        const float rs = rsqrtf(ss * (1.f / 256.f) + 1e-6f);
        float4 w0 = *(const float4*)(qw + l * 8);
        float4 w1 = *(const float4*)(qw + l * 8 + 4);
        float wa[8] = { w0.x, w0.y, w0.z, w0.w, w1.x, w1.y, w1.z, w1.w };
        float xn[8];
#pragma unroll
        for (int j = 0; j < 8; ++j) xn[j] = x[j] * rs * (1.f + wa[j]);
        const int d0 = (l * 8) & 127;
        float4 c0 = *(const float4*)(ct + s * 128 + d0);
        float4 c1 = *(const float4*)(ct + s * 128 + d0 + 4);
        float4 s0 = *(const float4*)(st + s * 128 + d0);
        float4 s1 = *(const float4*)(st + s * 128 + d0 + 4);
        float cc[8] = { c0.x, c0.y, c0.z, c0.w, c1.x, c1.y, c1.z, c1.w };
        float sn[8] = { s0.x, s0.y, s0.z, s0.w, s1.x, s1.y, s1.z, s1.w };
        const bool upper = (l >= 16);
        bf16x8 oh;
#pragma unroll
        for (int j = 0; j < 8; ++j) {
            float pn = __shfl_xor(xn[j], 16);
            float rot = upper ? pn : -pn;
            oh[j] = (bf16_t)(xn[j] * cc[j] + rot * sn[j]);
        }
        *(bf16x8*)base = oh;
    } else {
        const int tk = t - 256;
        const int h = tk >> 6, l = tk & 63;
        const bf16_t* base = kraw + (size_t)s * 1024 + h * 256 + l * 4;
        bf16x4 hv = *(const bf16x4*)base;
        float x[4], ss = 0.f;
#pragma unroll
        for (int j = 0; j < 4; ++j) { x[j] = (float)hv[j]; ss += x[j] * x[j]; }
#pragma unroll
        for (int mk = 1; mk < 64; mk <<= 1) ss += __shfl_xor(ss, mk);
        const float rs = rsqrtf(ss * (1.f / 256.f) + 1e-6f);
        float4 w0 = *(const float4*)(kw + l * 4);
        float wa[4] = { w0.x, w0.y, w0.z, w0.w };
        float xn[4];
#pragma unroll
        for (int j = 0; j < 4; ++j) xn[j] = x[j] * rs * (1.f + wa[j]);
        const int d0 = (l * 4) & 127;
        float4 c0 = *(const float4*)(ct + s * 128 + d0);
        float4 s0 = *(const float4*)(st + s * 128 + d0);
        float cc[4] = { c0.x, c0.y, c0.z, c0.w };
        float sn[4] = { s0.x, s0.y, s0.z, s0.w };
        const bool upper = (l >= 32);
        bf16x4 oh;
#pragma unroll
        for (int j = 0; j < 4; ++j) {
            float pn = __shfl_xor(xn[j], 32);
            float rot = upper ? pn : -pn;
            oh[j] = (bf16_t)(xn[j] * cc[j] + rot * sn[j]);
        }
        bf16_t* dst = kb2 + (size_t)h * 1048576 + (size_t)(s >> 5) * 8192
                    + (s & 31) * 256 + (((l >> 1) ^ (s & 7)) << 3) + (l & 1) * 4;
        *(bf16x4*)dst = oh;
    }
}

// ---------------------------------------------------------------------------
// Sliding-window GQA flash attention, no-max softmax, pre-tiled K/V.
// WIDE blocks: 8 waves = 128 q-rows per block, grid (8 h, 32 qt2).
// Window union spans <=36 tiles/block (vs 2x34 before) -> staging and
// barrier mass per q-row halves.  K dbuf + V single-buffer LDS (58 KB).
// ---------------------------------------------------------------------------
__global__ __launch_bounds__(512)
void attn_fwd9(const bf16_t* __restrict__ qb, const bf16_t* __restrict__ kb2,
               const bf16_t* __restrict__ vt2, bf16_t* __restrict__ attn)
{
    __shared__ __attribute__((aligned(16))) char smem[3 * 16384];
    __shared__ __attribute__((aligned(16))) bf16_t P[8][16][40];
    const int tid = threadIdx.x, lane = tid & 63, wid = tid >> 6;
    const int g = lane >> 4, c16 = lane & 15;
    const int h = blockIdx.x, kvh = h >> 1;
    const int by = blockIdx.y;
    const int qt2 = (by & 1) ? (31 - (by >> 1)) : (by >> 1);  // balance pair
    const int qrow0 = qt2 * 128 + wid * 16;

    const char* kslab = (const char*)kb2 + (size_t)kvh * 2097152;
    const char* vslab = (const char*)vt2 + (size_t)kvh * 2097152;

    bf16x8 qf[8];
#pragma unroll
    for (int c = 0; c < 8; ++c)
        qf[c] = *(const bf16x8*)(qb + (size_t)(qrow0 + c16) * 2048 + h * 256 + c * 32 + g * 8);

    float lrow[4] = { 0.f, 0.f, 0.f, 0.f };
    f32x4 acc[16];
#pragma unroll
    for (int nd = 0; nd < 16; ++nd) acc[nd] = (f32x4)(0.f);

    auto STAGE_K = [&](int buf, int kt) {
        char* Kd = smem + buf * 16384;
        const char* ks = kslab + (size_t)kt * 16384;
#pragma unroll
        for (int j = 0; j < 2; ++j)
            GLD_LDS16(ks + (size_t)(j * 512 + tid) * 16, Kd + (j * 512 + wid * 64) * 16);
    };
    auto STAGE_V = [&](int kt) {
        char* Vd = smem + 32768;
        const char* vs = vslab + (size_t)kt * 16384;
#pragma unroll
        for (int j = 0; j < 2; ++j)
            GLD_LDS16(vs + (size_t)(j * 512 + tid) * 16, Vd + (j * 512 + wid * 64) * 16);
    };

    const int ktb_lo = (qt2 >= 8) ? 4 * qt2 - 32 : 0;
    const int ktb_hi = 4 * qt2 + 3;
    int cur = 0;
    STAGE_K(0, ktb_lo);
    __syncthreads();

    const int swk = (c16 & 7) << 4;
    const int swv = (g ^ (c16 & 3)) << 4;
    const float S2 = 0.090168441f;   // 2^-4 * log2(e)

    for (int kt = ktb_lo; kt <= ktb_hi; ++kt) {
        STAGE_V(kt);
        if (kt < ktb_hi) STAGE_K(cur ^ 1, kt + 1);

        const bool rel = (kt * 32 <= qrow0 + 15) && (kt * 32 + 31 >= qrow0 - 1023);
        float p2[2][4];
        if (rel) {
            const char* Kc = smem + cur * 16384;
            f32x4 scA[2], scB[2];
#pragma unroll
            for (int n = 0; n < 2; ++n) { scA[n] = (f32x4)(0.f); scB[n] = (f32x4)(0.f); }
            __builtin_amdgcn_s_setprio(1);
#pragma unroll
            for (int n = 0; n < 2; ++n) {
                const char* kr = Kc + (n * 16 + c16) * 512;
#pragma unroll
                for (int c = 0; c < 4; ++c) {
                    bf16x8 kf = *(const bf16x8*)(kr + ((((c * 4 + g) << 4) ^ swk)));
                    scA[n] = __builtin_amdgcn_mfma_f32_16x16x32_bf16(qf[c], kf, scA[n], 0, 0, 0);
                }
#pragma unroll
                for (int c = 4; c < 8; ++c) {
                    bf16x8 kf = *(const bf16x8*)(kr + ((((c * 4 + g) << 4) ^ swk)));
                    scB[n] = __builtin_amdgcn_mfma_f32_16x16x32_bf16(qf[c], kf, scB[n], 0, 0, 0);
                }
            }
            __builtin_amdgcn_s_setprio(0);

            const bool fullv = (kt * 32 + 31 <= qrow0) && (kt * 32 >= qrow0 - 1008);
            if (fullv) {
#pragma unroll
                for (int n = 0; n < 2; ++n)
#pragma unroll
                    for (int r = 0; r < 4; ++r)
                        p2[n][r] = __builtin_amdgcn_exp2f((scA[n][r] + scB[n][r]) * S2);
            } else {
#pragma unroll
                for (int n = 0; n < 2; ++n) {
                    const int key = kt * 32 + n * 16 + c16;
#pragma unroll
                    for (int r = 0; r < 4; ++r) {
                        const int q = qrow0 + g * 4 + r;
                        bool valid = (key <= q) && (q - key < 1024);
                        float e = __builtin_amdgcn_exp2f((scA[n][r] + scB[n][r]) * S2);
                        p2[n][r] = valid ? e : 0.f;
                    }
                }
            }
#pragma unroll
            for (int n = 0; n < 2; ++n)
#pragma unroll
                for (int r = 0; r < 4; ++r) lrow[r] += p2[n][r];

#pragma unroll
            for (int n = 0; n < 2; ++n)
#pragma unroll
                for (int r = 0; r < 4; ++r)
                    P[wid][g * 4 + r][n * 16 + c16] = (bf16_t)p2[n][r];
        }
        __syncthreads();   // V(kt) + K(kt+1) landed; Kc reads done

        if (rel) {
            const char* Vc = smem + 32768;
            bf16x8 pa = *(const bf16x8*)(&P[wid][c16][g * 8]);
            __builtin_amdgcn_s_setprio(1);
#pragma unroll
            for (int nd = 0; nd < 16; ++nd) {
                bf16x8 vf = *(const bf16x8*)(Vc + (nd * 16 + c16) * 64 + swv);
                acc[nd] = __builtin_amdgcn_mfma_f32_16x16x32_bf16(pa, vf, acc[nd], 0, 0, 0);
            }
            __builtin_amdgcn_s_setprio(0);
        }
        __syncthreads();   // all waves done with V buffer
        cur ^= 1;
    }

#pragma unroll
    for (int mk = 1; mk < 16; mk <<= 1)
#pragma unroll
        for (int r = 0; r < 4; ++r) lrow[r] += __shfl_xor(lrow[r], mk);

    float inv[4];
#pragma unroll
    for (int r = 0; r < 4; ++r) inv[r] = 1.f / lrow[r];
#pragma unroll
    for (int nd = 0; nd < 16; ++nd)
#pragma unroll
        for (int r = 0; r < 4; ++r) {
            int row = qrow0 + g * 4 + r;
            attn[(size_t)row * 2048 + h * 256 + nd * 16 + c16] =
                (bf16_t)(acc[nd][r] * inv[r]);
        }
}

// ---------------------------------------------------------------------------
// Workspace (peak ~79.7 MB, phase-aliased):
//   hs_bf [0,          20,971,520)  (dead after gemm1)
//   qb    [20,971,520, 37,748,736)
//   kb_raw[37,748,736, 46,137,344)  (dead after norm_qk)
//   vt2   [46,137,344, 54,525,952)  tiled+swizzled
//   Bh    [54,525,952, 75,497,472)  (dead after gemm1)
//   kb2   [54,525,952, 62,914,560)  (over dead Bh; by norm_qk)
//   woh   [62,914,560, 73,400,320)  (over dead Bh tail; by norm_qk)
//   ct    [75,497,472, 77,594,624)
//   st    [77,594,624, 79,691,776)
//   attnb [0,          16,777,216)  (over dead hs_bf)
// ---------------------------------------------------------------------------
extern "C" void kernel_launch(void* const* d_in, const int* in_sizes, int n_in,
                              void* d_out, int out_size, void* d_ws, size_t ws_size,
                              hipStream_t stream)
{
    (void)in_sizes; (void)n_in; (void)out_size; (void)ws_size;
    const float* hs  = (const float*)d_in[0];
    const float* wq  = (const float*)d_in[3];
    const float* wk  = (const float*)d_in[4];
    const float* wv  = (const float*)d_in[5];
    const float* wo  = (const float*)d_in[6];
    const float* qnw = (const float*)d_in[7];
    const float* knw = (const float*)d_in[8];

    char* ws = (char*)d_ws;
    bf16_t* hs_bf = (bf16_t*)(ws);
    bf16_t* qb    = (bf16_t*)(ws + 20971520);
    bf16_t* kraw  = (bf16_t*)(ws + 37748736);
    bf16_t* vt2   = (bf16_t*)(ws + 46137344);
    bf16_t* Bh    = (bf16_t*)(ws + 54525952);
    bf16_t* kb2   = (bf16_t*)(ws + 54525952);
    bf16_t* woh   = (bf16_t*)(ws + 62914560);
    float*  ct    = (float*)(ws + 75497472);
    float*  st    = (float*)(ws + 77594624);
    bf16_t* attnb = (bf16_t*)(ws);

    // 1. fused prep: hs->bf16 + weight transposes + rope tables
    prep<<<14848, 256, 0, stream>>>(hs, hs_bf, wq, wk, wv, Bh, ct, st);

    // 2. fused qkv projection (8-phase 256^2 + XCD swizzle)
    gemm1<<<dim3(16, 16), 512, 0, stream>>>(hs_bf, Bh, qb, kraw, vt2);

    // 3. fused norms + wo transpose (kb2/woh over dead Bh)
    norm_qk<<<4736, 512, 0, stream>>>(qb, kraw, kb2, qnw, knw, ct, st, wo, woh);

    // 4. attention (wide blocks: 128 q-rows, 8 waves; K dbuf + V sbuf)
    attn_fwd9<<<dim3(8, 32), 512, 0, stream>>>(qb, kb2, vt2, attnb);

    // 5. output projection (8-phase 256^2 + XCD swizzle)
    gemm2p<<<dim3(10, 16), 512, 0, stream>>>(attnb, woh, (float*)d_out);
}

// Round 19
// 230.349 us; speedup vs baseline: 1.0127x; 1.0127x over previous
//
#include <hip/hip_runtime.h>
#include <stdint.h>
#include <math.h>

typedef __bf16 bf16_t;
typedef __bf16 bf16x8 __attribute__((ext_vector_type(8)));
typedef __bf16 bf16x4 __attribute__((ext_vector_type(4)));
typedef float f32x4 __attribute__((ext_vector_type(4)));

#define GLD_LDS16(g, l)                                             \
    __builtin_amdgcn_global_load_lds(                               \
        (const __attribute__((address_space(1))) void*)(g),         \
        (__attribute__((address_space(3))) void*)(l), 16, 0, 0)

#define WAITV(N) asm volatile("s_waitcnt vmcnt(" #N ")" ::: "memory")
#define BARRIER() do { __builtin_amdgcn_sched_barrier(0);           \
                       __builtin_amdgcn_s_barrier();                \
                       __builtin_amdgcn_sched_barrier(0); } while (0)

// ---------------------------------------------------------------------------
// prep: fused weight transposes (wq/wk/wv -> Bh panel) + RoPE tables +
// hs fp32->bf16 conv.
// ---------------------------------------------------------------------------
__global__ __launch_bounds__(256)
void prep(const float* __restrict__ hs, bf16_t* __restrict__ hsb,
          const float* __restrict__ wq, const float* __restrict__ wk,
          const float* __restrict__ wv, bf16_t* __restrict__ Bh,
          float* __restrict__ ct, float* __restrict__ st)
{
    const int b = blockIdx.x;
    if (b >= 4608) {                       // conv: 10240 blocks x 256 x 4
        int i = (b - 4608) * 256 + threadIdx.x;
        float4 v = ((const float4*)hs)[i];
        bf16x4 o = { (bf16_t)v.x, (bf16_t)v.y, (bf16_t)v.z, (bf16_t)v.w };
        ((bf16x4*)hsb)[i] = o;
        return;
    }
    if (b >= 2560) {                       // rope tables: 2048 blocks
        int t = (b - 2560) * 256 + threadIdx.x;   // 4096*128
        int s = t >> 7, j = t & 127;
        double inv = exp2((double)j * (-13.28771237954945 / 128.0));
        double ang = fmod((double)s * inv, 6.283185307179586476925286766559);
        ct[t] = (float)cos(ang);
        st[t] = (float)sin(ang);
        return;
    }
    const float* src; bf16_t* dst; int C, bx, by;
    if (b < 1280)      { src = wq; dst = Bh;                          C = 2048; bx = b % 32;          by = b / 32; }
    else if (b < 1920) { src = wk; dst = Bh + (size_t)2048 * 2560;    C = 1024; bx = (b - 1280) % 16; by = (b - 1280) / 16; }
    else               { src = wv; dst = Bh + (size_t)3072 * 2560;    C = 1024; bx = (b - 1920) % 16; by = (b - 1920) / 16; }
    const int R = 2560;
    __shared__ float t[64][65];
    const int r0 = by * 64, c0 = bx * 64;
#pragma unroll
    for (int i = 0; i < 16; ++i) {
        int f = threadIdx.x + i * 256;
        int r = f >> 6, c = f & 63;
        t[r][c] = src[(size_t)(r0 + r) * C + c0 + c];
    }
    __syncthreads();
#pragma unroll
    for (int i = 0; i < 16; ++i) {
        int f = threadIdx.x + i * 256;
        int r = f >> 6, c = f & 63;
        dst[(size_t)(c0 + r) * R + r0 + c] = (bf16_t)t[c][r];
    }
}

// ---------------------------------------------------------------------------
// GEMM1 (fused qkv), 8-phase 256x256 tile, BK=64, 8 waves (2Mx4N), 128 KiB
// LDS double-buffer, XOR-swizzled, counted vmcnt; XCD-chunked block swizzle.
// ---------------------------------------------------------------------------
__global__ __launch_bounds__(512, 2)
void gemm1(const bf16_t* __restrict__ A, const bf16_t* __restrict__ Bh,
           bf16_t* __restrict__ qb, bf16_t* __restrict__ kb,
           bf16_t* __restrict__ vt)
{
    __shared__ __attribute__((aligned(16))) char smem[131072];
    const int tid = threadIdx.x, lane = tid & 63, wid = tid >> 6;
    const int g = lane >> 4, c16 = lane & 15;
    const int wm = wid >> 2, wn = wid & 3;          // 2 x 4 wave grid
    const int bid = blockIdx.y * 16 + blockIdx.x;
    const int nb = (bid & 7) * 32 + (bid >> 3);
    const int m0 = (nb >> 4) * 256, n0 = (nb & 15) * 256;
    const int swz = c16 & 7;
    const int NT = 40;                               // 2560 / 64

    f32x4 acc[8][4];
#pragma unroll
    for (int m = 0; m < 8; ++m)
#pragma unroll
        for (int n = 0; n < 4; ++n) acc[m][n] = (f32x4)(0.f);

    auto STAGE_A = [&](int dbuf, int kt, int half) {
#pragma unroll
        for (int pl = 0; pl < 2; ++pl) {
            int c = pl * 512 + tid;
            int row = c >> 3, b = c & 7;
            GLD_LDS16(A + (size_t)(m0 + half * 128 + row) * 2560 + kt * 64
                        + ((b ^ (row & 7)) << 3),
                      smem + dbuf * 65536 + half * 16384
                        + (pl * 512 + wid * 64) * 16);
        }
    };
    auto STAGE_B = [&](int dbuf, int kt, int qp) {
#pragma unroll
        for (int pl = 0; pl < 2; ++pl) {
            int c = pl * 512 + tid;
            int u = c >> 3, b = c & 7;
            int row = ((u >> 5) << 6) + qp * 32 + (u & 31);
            int u0 = pl * 64 + wid * 8;
            int row0 = ((u0 >> 5) << 6) + qp * 32 + (u0 & 31);
            GLD_LDS16(Bh + (size_t)(n0 + row) * 2560 + kt * 64
                        + ((b ^ (row & 7)) << 3),
                      smem + dbuf * 65536 + 32768 + row0 * 128);
        }
    };

    STAGE_A(0, 0, 0); STAGE_A(0, 0, 1); STAGE_B(0, 0, 0); STAGE_B(0, 0, 1);
    WAITV(2);
    BARRIER();

    for (int t = 0; t < NT; ++t) {
        const int buf = t & 1, nbuf = buf ^ 1;
        const char* Ab = smem + buf * 65536;
        const char* Bb = smem + buf * 65536 + 32768;
        auto rdA = [&](int m, int kk) {
            return *(const bf16x8*)(Ab + (wm * 128 + m * 16 + c16) * 128
                                       + (((kk * 4 + g) ^ swz) << 4));
        };
        auto rdB = [&](int n, int kk) {
            return *(const bf16x8*)(Bb + (wn * 64 + n * 16 + c16) * 128
                                       + (((kk * 4 + g) ^ swz) << 4));
        };
        bf16x8 a[8], b0, b1, b2, b3;

        // ---- P0 ------------------------------------------------------
#pragma unroll
        for (int m = 0; m < 8; ++m) a[m] = rdA(m, 0);
        b0 = rdB(0, 0); b1 = rdB(1, 0);
        if (t + 1 < NT) STAGE_A(nbuf, t + 1, 0);
        BARRIER();
        __builtin_amdgcn_s_setprio(1);
#pragma unroll
        for (int m = 0; m < 8; ++m) {
            acc[m][0] = __builtin_amdgcn_mfma_f32_16x16x32_bf16(a[m], b0, acc[m][0], 0, 0, 0);
            acc[m][1] = __builtin_amdgcn_mfma_f32_16x16x32_bf16(a[m], b1, acc[m][1], 0, 0, 0);
        }
        __builtin_amdgcn_s_setprio(0);
        if (t + 1 < NT) { WAITV(2); } else { WAITV(0); }
        BARRIER();

        // ---- P1 ------------------------------------------------------
        b2 = rdB(2, 0); b3 = rdB(3, 0);
        if (t + 1 < NT) STAGE_A(nbuf, t + 1, 1);
        BARRIER();
        __builtin_amdgcn_s_setprio(1);
#pragma unroll
        for (int m = 0; m < 8; ++m) {
            acc[m][2] = __builtin_amdgcn_mfma_f32_16x16x32_bf16(a[m], b2, acc[m][2], 0, 0, 0);
            acc[m][3] = __builtin_amdgcn_mfma_f32_16x16x32_bf16(a[m], b3, acc[m][3], 0, 0, 0);
        }
        __builtin_amdgcn_s_setprio(0);
        BARRIER();

        // ---- P2 ------------------------------------------------------
#pragma unroll
        for (int m = 0; m < 8; ++m) a[m] = rdA(m, 1);
        b0 = rdB(0, 1); b1 = rdB(1, 1);
        if (t + 1 < NT) STAGE_B(nbuf, t + 1, 0);
        BARRIER();
        __builtin_amdgcn_s_setprio(1);
#pragma unroll
        for (int m = 0; m < 8; ++m) {
            acc[m][0] = __builtin_amdgcn_mfma_f32_16x16x32_bf16(a[m], b0, acc[m][0], 0, 0, 0);
            acc[m][1] = __builtin_amdgcn_mfma_f32_16x16x32_bf16(a[m], b1, acc[m][1], 0, 0, 0);
        }
        __builtin_amdgcn_s_setprio(0);
        BARRIER();

        // ---- P3 ------------------------------------------------------
        b2 = rdB(2, 1); b3 = rdB(3, 1);
        if (t + 1 < NT) STAGE_B(nbuf, t + 1, 1);
        BARRIER();
        __builtin_amdgcn_s_setprio(1);
#pragma unroll
        for (int m = 0; m < 8; ++m) {
            acc[m][2] = __builtin_amdgcn_mfma_f32_16x16x32_bf16(a[m], b2, acc[m][2], 0, 0, 0);
            acc[m][3] = __builtin_amdgcn_mfma_f32_16x16x32_bf16(a[m], b3, acc[m][3], 0, 0, 0);
        }
        __builtin_amdgcn_s_setprio(0);
        if (t + 1 < NT) WAITV(2);
        BARRIER();
    }

    if (n0 < 2048) {          // q region
#pragma unroll
        for (int m = 0; m < 8; ++m)
#pragma unroll
            for (int n = 0; n < 4; ++n) {
                int col = n0 + wn * 64 + n * 16 + c16;
                int rowb = m0 + wm * 128 + m * 16 + g * 4;
#pragma unroll
                for (int r = 0; r < 4; ++r)
                    qb[(size_t)(rowb + r) * 2048 + col] = (bf16_t)acc[m][n][r];
            }
    } else if (n0 < 3072) {   // k region (raw, re-tiled by norm_qk)
#pragma unroll
        for (int m = 0; m < 8; ++m)
#pragma unroll
            for (int n = 0; n < 4; ++n) {
                int col = n0 + wn * 64 + n * 16 + c16 - 2048;
                int rowb = m0 + wm * 128 + m * 16 + g * 4;
#pragma unroll
                for (int r = 0; r < 4; ++r)
                    kb[(size_t)(rowb + r) * 1024 + col] = (bf16_t)acc[m][n][r];
            }
    } else {                  // v region -> vt2 tiled + swizzled
#pragma unroll
        for (int m = 0; m < 8; ++m)
#pragma unroll
            for (int n = 0; n < 4; ++n) {
                int d = n0 + wn * 64 + n * 16 + c16 - 3072;
                int rowb = m0 + wm * 128 + m * 16 + g * 4;
                int kvh_ = d >> 8, dd = d & 255;
                int kt = rowb >> 5, key = rowb & 31;
                bf16x4 hv;
#pragma unroll
                for (int r = 0; r < 4; ++r) hv[r] = (bf16_t)acc[m][n][r];
                size_t off = (size_t)kvh_ * 1048576 + (size_t)kt * 8192
                           + dd * 32 + (((key >> 3) ^ (dd & 3)) << 3) + (key & 7);
                *(bf16x4*)(vt + off) = hv;
            }
    }
}

// ---------------------------------------------------------------------------
// GEMM2, same template/schedule, K = 2048 -> NT = 32, fp32 out; XCD swizzle.
// ---------------------------------------------------------------------------
__global__ __launch_bounds__(512, 2)
void gemm2p(const bf16_t* __restrict__ A, const bf16_t* __restrict__ Bh,
            float* __restrict__ C)
{
    __shared__ __attribute__((aligned(16))) char smem[131072];
    const int tid = threadIdx.x, lane = tid & 63, wid = tid >> 6;
    const int g = lane >> 4, c16 = lane & 15;
    const int wm = wid >> 2, wn = wid & 3;
    const int bid = blockIdx.y * 10 + blockIdx.x;
    const int nb = (bid & 7) * 20 + (bid >> 3);
    const int m0 = (nb / 10) * 256, n0 = (nb % 10) * 256;
    const int swz = c16 & 7;
    const int NT = 32;                               // 2048 / 64

    f32x4 acc[8][4];
#pragma unroll
    for (int m = 0; m < 8; ++m)
#pragma unroll
        for (int n = 0; n < 4; ++n) acc[m][n] = (f32x4)(0.f);

    auto STAGE_A = [&](int dbuf, int kt, int half) {
#pragma unroll
        for (int pl = 0; pl < 2; ++pl) {
            int c = pl * 512 + tid;
            int row = c >> 3, b = c & 7;
            GLD_LDS16(A + (size_t)(m0 + half * 128 + row) * 2048 + kt * 64
                        + ((b ^ (row & 7)) << 3),
                      smem + dbuf * 65536 + half * 16384
                        + (pl * 512 + wid * 64) * 16);
        }
    };
    auto STAGE_B = [&](int dbuf, int kt, int qp) {
#pragma unroll
        for (int pl = 0; pl < 2; ++pl) {
            int c = pl * 512 + tid;
            int u = c >> 3, b = c & 7;
            int row = ((u >> 5) << 6) + qp * 32 + (u & 31);
            int u0 = pl * 64 + wid * 8;
            int row0 = ((u0 >> 5) << 6) + qp * 32 + (u0 & 31);
            GLD_LDS16(Bh + (size_t)(n0 + row) * 2048 + kt * 64
                        + ((b ^ (row & 7)) << 3),
                      smem + dbuf * 65536 + 32768 + row0 * 128);
        }
    };

    STAGE_A(0, 0, 0); STAGE_A(0, 0, 1); STAGE_B(0, 0, 0); STAGE_B(0, 0, 1);
    WAITV(2);
    BARRIER();

    for (int t = 0; t < NT; ++t) {
        const int buf = t & 1, nbuf = buf ^ 1;
        const char* Ab = smem + buf * 65536;
        const char* Bb = smem + buf * 65536 + 32768;
        auto rdA = [&](int m, int kk) {
            return *(const bf16x8*)(Ab + (wm * 128 + m * 16 + c16) * 128
                                       + (((kk * 4 + g) ^ swz) << 4));
        };
        auto rdB = [&](int n, int kk) {
            return *(const bf16x8*)(Bb + (wn * 64 + n * 16 + c16) * 128
                                       + (((kk * 4 + g) ^ swz) << 4));
        };
        bf16x8 a[8], b0, b1, b2, b3;

#pragma unroll
        for (int m = 0; m < 8; ++m) a[m] = rdA(m, 0);
        b0 = rdB(0, 0); b1 = rdB(1, 0);
        if (t + 1 < NT) STAGE_A(nbuf, t + 1, 0);
        BARRIER();
        __builtin_amdgcn_s_setprio(1);
#pragma unroll
        for (int m = 0; m < 8; ++m) {
            acc[m][0] = __builtin_amdgcn_mfma_f32_16x16x32_bf16(a[m], b0, acc[m][0], 0, 0, 0);
            acc[m][1] = __builtin_amdgcn_mfma_f32_16x16x32_bf16(a[m], b1, acc[m][1], 0, 0, 0);
        }
        __builtin_amdgcn_s_setprio(0);
        if (t + 1 < NT) { WAITV(2); } else { WAITV(0); }
        BARRIER();

        b2 = rdB(2, 0); b3 = rdB(3, 0);
        if (t + 1 < NT) STAGE_A(nbuf, t + 1, 1);
        BARRIER();
        __builtin_amdgcn_s_setprio(1);
#pragma unroll
        for (int m = 0; m < 8; ++m) {
            acc[m][2] = __builtin_amdgcn_mfma_f32_16x16x32_bf16(a[m], b2, acc[m][2], 0, 0, 0);
            acc[m][3] = __builtin_amdgcn_mfma_f32_16x16x32_bf16(a[m], b3, acc[m][3], 0, 0, 0);
        }
        __builtin_amdgcn_s_setprio(0);
        BARRIER();

#pragma unroll
        for (int m = 0; m < 8; ++m) a[m] = rdA(m, 1);
        b0 = rdB(0, 1); b1 = rdB(1, 1);
        if (t + 1 < NT) STAGE_B(nbuf, t + 1, 0);
        BARRIER();
        __builtin_amdgcn_s_setprio(1);
#pragma unroll
        for (int m = 0; m < 8; ++m) {
            acc[m][0] = __builtin_amdgcn_mfma_f32_16x16x32_bf16(a[m], b0, acc[m][0], 0, 0, 0);
            acc[m][1] = __builtin_amdgcn_mfma_f32_16x16x32_bf16(a[m], b1, acc[m][1], 0, 0, 0);
        }
        __builtin_amdgcn_s_setprio(0);
        BARRIER();

        b2 = rdB(2, 1); b3 = rdB(3, 1);
        if (t + 1 < NT) STAGE_B(nbuf, t + 1, 1);
        BARRIER();
        __builtin_amdgcn_s_setprio(1);
#pragma unroll
        for (int m = 0; m < 8; ++m) {
            acc[m][2] = __builtin_amdgcn_mfma_f32_16x16x32_bf16(a[m], b2, acc[m][2], 0, 0, 0);
            acc[m][3] = __builtin_amdgcn_mfma_f32_16x16x32_bf16(a[m], b3, acc[m][3], 0, 0, 0);
        }
        __builtin_amdgcn_s_setprio(0);
        if (t + 1 < NT) WAITV(2);
        BARRIER();
    }

#pragma unroll
    for (int m = 0; m < 8; ++m)
#pragma unroll
        for (int n = 0; n < 4; ++n) {
            int col = n0 + wn * 64 + n * 16 + c16;
            int rowb = m0 + wm * 128 + m * 16 + g * 4;
#pragma unroll
            for (int r = 0; r < 4; ++r)
                C[(size_t)(rowb + r) * 2560 + col] = acc[m][n][r];
        }
}

// ---------------------------------------------------------------------------
// Fused RMSNorm + RoPE + wo-transpose.
// ---------------------------------------------------------------------------
__global__ __launch_bounds__(512)
void norm_qk(bf16_t* __restrict__ qb, const bf16_t* __restrict__ kraw,
             bf16_t* __restrict__ kb2, const float* __restrict__ qw,
             const float* __restrict__ kw, const float* __restrict__ ct,
             const float* __restrict__ st, const float* __restrict__ wo,
             bf16_t* __restrict__ woh)
{
    __shared__ float tt[2][64][65];
    const int s = blockIdx.x, t = threadIdx.x;
    if (s >= 4096) {          // wo transpose: 2 tiles per block
        const int half = t >> 8, tl = t & 255;
        const int tileIdx = (s - 4096) * 2 + half;   // 0..1279
        const int bx = tileIdx % 40, by = tileIdx / 40;
        const int r0 = by * 64, c0 = bx * 64;
#pragma unroll
        for (int i = 0; i < 16; ++i) {
            int f = tl + i * 256;
            int r = f >> 6, c = f & 63;
            tt[half][r][c] = wo[(size_t)(r0 + r) * 2560 + c0 + c];
        }
        __syncthreads();
#pragma unroll
        for (int i = 0; i < 16; ++i) {
            int f = tl + i * 256;
            int r = f >> 6, c = f & 63;
            woh[(size_t)(c0 + r) * 2048 + r0 + c] = (bf16_t)tt[half][c][r];
        }
        return;
    }
    if (t < 256) {
        const int h = t >> 5, l = t & 31;
        bf16_t* base = qb + (size_t)s * 2048 + h * 256 + l * 8;
        bf16x8 hv = *(const bf16x8*)base;
        float x[8], ss = 0.f;
#pragma unroll
        for (int j = 0; j < 8; ++j) { x[j] = (float)hv[j]; ss += x[j] * x[j]; }
#pragma unroll
        for (int mk = 1; mk < 32; mk <<= 1) ss += __shfl_xor(ss, mk);
        const float rs = rsqrtf(ss * (1.f / 256.f) + 1e-6f);
        float4 w0 = *(const float4*)(qw + l * 8);
        float4 w1 = *(const float4*)(qw + l * 8 + 4);
        float wa[8] = { w0.x, w0.y, w0.z, w0.w, w1.x, w1.y, w1.z, w1.w };
        float xn[8];
#pragma unroll
        for (int j = 0; j < 8; ++j) xn[j] = x[j] * rs * (1.f + wa[j]);
        const int d0 = (l * 8) & 127;
        float4 c0 = *(const float4*)(ct + s * 128 + d0);
        float4 c1 = *(const float4*)(ct + s * 128 + d0 + 4);
        float4 s0 = *(const float4*)(st + s * 128 + d0);
        float4 s1 = *(const float4*)(st + s * 128 + d0 + 4);
        float cc[8] = { c0.x, c0.y, c0.z, c0.w, c1.x, c1.y, c1.z, c1.w };
        float sn[8] = { s0.x, s0.y, s0.z, s0.w, s1.x, s1.y, s1.z, s1.w };
        const bool upper = (l >= 16);
        bf16x8 oh;
#pragma unroll
        for (int j = 0; j < 8; ++j) {
            float pn = __shfl_xor(xn[j], 16);
            float rot = upper ? pn : -pn;
            oh[j] = (bf16_t)(xn[j] * cc[j] + rot * sn[j]);
        }
        *(bf16x8*)base = oh;
    } else {
        const int tk = t - 256;
        const int h = tk >> 6, l = tk & 63;
        const bf16_t* base = kraw + (size_t)s * 1024 + h * 256 + l * 4;
        bf16x4 hv = *(const bf16x4*)base;
        float x[4], ss = 0.f;
#pragma unroll
        for (int j = 0; j < 4; ++j) { x[j] = (float)hv[j]; ss += x[j] * x[j]; }
#pragma unroll
        for (int mk = 1; mk < 64; mk <<= 1) ss += __shfl_xor(ss, mk);
        const float rs = rsqrtf(ss * (1.f / 256.f) + 1e-6f);
        float4 w0 = *(const float4*)(kw + l * 4);
        float wa[4] = { w0.x, w0.y, w0.z, w0.w };
        float xn[4];
#pragma unroll
        for (int j = 0; j < 4; ++j) xn[j] = x[j] * rs * (1.f + wa[j]);
        const int d0 = (l * 4) & 127;
        float4 c0 = *(const float4*)(ct + s * 128 + d0);
        float4 s0 = *(const float4*)(st + s * 128 + d0);
        float cc[4] = { c0.x, c0.y, c0.z, c0.w };
        float sn[4] = { s0.x, s0.y, s0.z, s0.w };
        const bool upper = (l >= 32);
        bf16x4 oh;
#pragma unroll
        for (int j = 0; j < 4; ++j) {
            float pn = __shfl_xor(xn[j], 32);
            float rot = upper ? pn : -pn;
            oh[j] = (bf16_t)(xn[j] * cc[j] + rot * sn[j]);
        }
        bf16_t* dst = kb2 + (size_t)h * 1048576 + (size_t)(s >> 5) * 8192
                    + (s & 31) * 256 + (((l >> 1) ^ (s & 7)) << 3) + (l & 1) * 4;
        *(bf16x4*)dst = oh;
    }
}

// ---------------------------------------------------------------------------
// Sliding-window GQA flash attention, no-max softmax, pre-tiled K/V.
// K dbuf + V single-buffer LDS (round-17 best config).
// ---------------------------------------------------------------------------
__global__ __launch_bounds__(256)
void attn_fwd8(const bf16_t* __restrict__ qb, const bf16_t* __restrict__ kb2,
               const bf16_t* __restrict__ vt2, bf16_t* __restrict__ attn)
{
    __shared__ __attribute__((aligned(16))) char smem[3 * 16384];
    __shared__ __attribute__((aligned(16))) bf16_t P[4][16][40];
    const int tid = threadIdx.x, lane = tid & 63, wid = tid >> 6;
    const int g = lane >> 4, c16 = lane & 15;
    const int h = blockIdx.x, kvh = h >> 1;
    const int by = blockIdx.y;
    const int qt = (by & 1) ? (63 - (by >> 1)) : (by >> 1);   // balance pair
    const int qrow0 = qt * 64 + wid * 16;

    const char* kslab = (const char*)kb2 + (size_t)kvh * 2097152;
    const char* vslab = (const char*)vt2 + (size_t)kvh * 2097152;

    bf16x8 qf[8];
#pragma unroll
    for (int c = 0; c < 8; ++c)
        qf[c] = *(const bf16x8*)(qb + (size_t)(qrow0 + c16) * 2048 + h * 256 + c * 32 + g * 8);

    float lrow[4] = { 0.f, 0.f, 0.f, 0.f };
    f32x4 acc[16];
#pragma unroll
    for (int nd = 0; nd < 16; ++nd) acc[nd] = (f32x4)(0.f);

    auto STAGE_K = [&](int buf, int kt) {
        char* Kd = smem + buf * 16384;
        const char* ks = kslab + (size_t)kt * 16384;
#pragma unroll
        for (int j = 0; j < 4; ++j)
            GLD_LDS16(ks + (size_t)(j * 256 + tid) * 16, Kd + (j * 256 + wid * 64) * 16);
    };
    auto STAGE_V = [&](int kt) {
        char* Vd = smem + 32768;
        const char* vs = vslab + (size_t)kt * 16384;
#pragma unroll
        for (int j = 0; j < 4; ++j)
            GLD_LDS16(vs + (size_t)(j * 256 + tid) * 16, Vd + (j * 256 + wid * 64) * 16);
    };

    const int ktb_lo = (qt >= 16) ? 2 * qt - 32 : 0;
    const int ktb_hi = 2 * qt + 1;
    int cur = 0;
    STAGE_K(0, ktb_lo);
    __syncthreads();

    const int swk = (c16 & 7) << 4;
    const int swv = (g ^ (c16 & 3)) << 4;
    const float S2 = 0.090168441f;   // 2^-4 * log2(e)

    for (int kt = ktb_lo; kt <= ktb_hi; ++kt) {
        STAGE_V(kt);
        if (kt < ktb_hi) STAGE_K(cur ^ 1, kt + 1);

        const bool rel = (kt * 32 <= qrow0 + 15) && (kt * 32 + 31 >= qrow0 - 1023);
        float p2[2][4];
        if (rel) {
            const char* Kc = smem + cur * 16384;
            f32x4 scA[2], scB[2];
#pragma unroll
            for (int n = 0; n < 2; ++n) { scA[n] = (f32x4)(0.f); scB[n] = (f32x4)(0.f); }
            __builtin_amdgcn_s_setprio(1);
#pragma unroll
            for (int n = 0; n < 2; ++n) {
                const char* kr = Kc + (n * 16 + c16) * 512;
#pragma unroll
                for (int c = 0; c < 4; ++c) {
                    bf16x8 kf = *(const bf16x8*)(kr + ((((c * 4 + g) << 4) ^ swk)));
                    scA[n] = __builtin_amdgcn_mfma_f32_16x16x32_bf16(qf[c], kf, scA[n], 0, 0, 0);
                }
#pragma unroll
                for (int c = 4; c < 8; ++c) {
                    bf16x8 kf = *(const bf16x8*)(kr + ((((c * 4 + g) << 4) ^ swk)));
                    scB[n] = __builtin_amdgcn_mfma_f32_16x16x32_bf16(qf[c], kf, scB[n], 0, 0, 0);
                }
            }
            __builtin_amdgcn_s_setprio(0);

            const bool fullv = (kt * 32 + 31 <= qrow0) && (kt * 32 >= qrow0 - 1008);
            if (fullv) {
#pragma unroll
                for (int n = 0; n < 2; ++n)
#pragma unroll
                    for (int r = 0; r < 4; ++r)
                        p2[n][r] = __builtin_amdgcn_exp2f((scA[n][r] + scB[n][r]) * S2);
            } else {
#pragma unroll
                for (int n = 0; n < 2; ++n) {
                    const int key = kt * 32 + n * 16 + c16;
#pragma unroll
                    for (int r = 0; r < 4; ++r) {
                        const int q = qrow0 + g * 4 + r;
                        bool valid = (key <= q) && (q - key < 1024);
                        float e = __builtin_amdgcn_exp2f((scA[n][r] + scB[n][r]) * S2);
                        p2[n][r] = valid ? e : 0.f;
                    }
                }
            }
#pragma unroll
            for (int n = 0; n < 2; ++n)
#pragma unroll
                for (int r = 0; r < 4; ++r) lrow[r] += p2[n][r];

#pragma unroll
            for (int n = 0; n < 2; ++n)
#pragma unroll
                for (int r = 0; r < 4; ++r)
                    P[wid][g * 4 + r][n * 16 + c16] = (bf16_t)p2[n][r];
        }
        __syncthreads();   // V(kt) + K(kt+1) landed; Kc reads done

        if (rel) {
            const char* Vc = smem + 32768;
            bf16x8 pa = *(const bf16x8*)(&P[wid][c16][g * 8]);
            __builtin_amdgcn_s_setprio(1);
#pragma unroll
            for (int nd = 0; nd < 16; ++nd) {
                bf16x8 vf = *(const bf16x8*)(Vc + (nd * 16 + c16) * 64 + swv);
                acc[nd] = __builtin_amdgcn_mfma_f32_16x16x32_bf16(pa, vf, acc[nd], 0, 0, 0);
            }
            __builtin_amdgcn_s_setprio(0);
        }
        __syncthreads();   // all waves done with V buffer
        cur ^= 1;
    }

#pragma unroll
    for (int mk = 1; mk < 16; mk <<= 1)
#pragma unroll
        for (int r = 0; r < 4; ++r) lrow[r] += __shfl_xor(lrow[r], mk);

    float inv[4];
#pragma unroll
    for (int r = 0; r < 4; ++r) inv[r] = 1.f / lrow[r];
#pragma unroll
    for (int nd = 0; nd < 16; ++nd)
#pragma unroll
        for (int r = 0; r < 4; ++r) {
            int row = qrow0 + g * 4 + r;
            attn[(size_t)row * 2048 + h * 256 + nd * 16 + c16] =
                (bf16_t)(acc[nd][r] * inv[r]);
        }
}

// ---------------------------------------------------------------------------
// Workspace (peak ~79.7 MB, phase-aliased):
//   hs_bf [0,          20,971,520)  (dead after gemm1)
//   qb    [20,971,520, 37,748,736)
//   kb_raw[37,748,736, 46,137,344)  (dead after norm_qk)
//   vt2   [46,137,344, 54,525,952)  tiled+swizzled
//   Bh    [54,525,952, 75,497,472)  (dead after gemm1)
//   kb2   [54,525,952, 62,914,560)  (over dead Bh; by norm_qk)
//   woh   [62,914,560, 73,400,320)  (over dead Bh tail; by norm_qk)
//   ct    [75,497,472, 77,594,624)
//   st    [77,594,624, 79,691,776)
//   attnb [0,          16,777,216)  (over dead hs_bf)
// ---------------------------------------------------------------------------
extern "C" void kernel_launch(void* const* d_in, const int* in_sizes, int n_in,
                              void* d_out, int out_size, void* d_ws, size_t ws_size,
                              hipStream_t stream)
{
    (void)in_sizes; (void)n_in; (void)out_size; (void)ws_size;
    const float* hs  = (const float*)d_in[0];
    const float* wq  = (const float*)d_in[3];
    const float* wk  = (const float*)d_in[4];
    const float* wv  = (const float*)d_in[5];
    const float* wo  = (const float*)d_in[6];
    const float* qnw = (const float*)d_in[7];
    const float* knw = (const float*)d_in[8];

    char* ws = (char*)d_ws;
    bf16_t* hs_bf = (bf16_t*)(ws);
    bf16_t* qb    = (bf16_t*)(ws + 20971520);
    bf16_t* kraw  = (bf16_t*)(ws + 37748736);
    bf16_t* vt2   = (bf16_t*)(ws + 46137344);
    bf16_t* Bh    = (bf16_t*)(ws + 54525952);
    bf16_t* kb2   = (bf16_t*)(ws + 54525952);
    bf16_t* woh   = (bf16_t*)(ws + 62914560);
    float*  ct    = (float*)(ws + 75497472);
    float*  st    = (float*)(ws + 77594624);
    bf16_t* attnb = (bf16_t*)(ws);

    // 1. fused prep: hs->bf16 + weight transposes + rope tables
    prep<<<14848, 256, 0, stream>>>(hs, hs_bf, wq, wk, wv, Bh, ct, st);

    // 2. fused qkv projection (8-phase 256^2 + XCD swizzle)
    gemm1<<<dim3(16, 16), 512, 0, stream>>>(hs_bf, Bh, qb, kraw, vt2);

    // 3. fused norms + wo transpose (kb2/woh over dead Bh)
    norm_qk<<<4736, 512, 0, stream>>>(qb, kraw, kb2, qnw, knw, ct, st, wo, woh);

    // 4. attention (K dbuf + V single-buffer LDS)
    attn_fwd8<<<dim3(8, 64), 256, 0, stream>>>(qb, kb2, vt2, attnb);

    // 5. output projection (8-phase 256^2 + XCD swizzle)
    gemm2p<<<dim3(10, 16), 512, 0, stream>>>(attnb, woh, (float*)d_out);
}